// Round 7
// baseline (349.258 us; speedup 1.0000x reference)
//
#include <hip/hip_runtime.h>

// B=256, T=256, C=512, H=64. fp32 in; f16 MFMA w/ fp32 acc.
// ws: qw (65536x64 f16) | kw | vt ([256][64][256] f16, V transposed) | wt ([3][64][512] f16)

typedef _Float16 half8 __attribute__((ext_vector_type(8)));
typedef float floatx4 __attribute__((ext_vector_type(4)));

#define MFMA16(a, b, c) __builtin_amdgcn_mfma_f32_16x16x32_f16((a), (b), (c), 0, 0, 0)

__device__ inline half8 cvt8(float4 a, float4 b) {
  half8 r;
  r[0] = (_Float16)a.x; r[1] = (_Float16)a.y; r[2] = (_Float16)a.z; r[3] = (_Float16)a.w;
  r[4] = (_Float16)b.x; r[5] = (_Float16)b.y; r[6] = (_Float16)b.z; r[7] = (_Float16)b.w;
  return r;
}

// ---- W transpose: W[512][64] f32 -> Wt[w][64][512] f16. grid 24 (3 W x 8 k-chunks).
__global__ __launch_bounds__(256) void wt_kernel(
    const float* __restrict__ Wq, const float* __restrict__ Wk,
    const float* __restrict__ Wv, _Float16* __restrict__ Wt) {
  __shared__ _Float16 t_lds[64][72];  // [n][k], stride 144B (16B-aligned rows)
  const int w = blockIdx.x >> 3, kb = blockIdx.x & 7;
  const float* W = (w == 0) ? Wq : (w == 1 ? Wk : Wv);
  const int tid = threadIdx.x;
  const int kk = tid >> 2;          // 0..63 k-row within chunk
  const int n0 = (tid & 3) * 16;    // 0,16,32,48
  const float4* src = (const float4*)(W + (size_t)(kb * 64 + kk) * 64 + n0);
  float4 f0 = src[0], f1 = src[1], f2 = src[2], f3 = src[3];
  t_lds[n0 +  0][kk] = (_Float16)f0.x; t_lds[n0 +  1][kk] = (_Float16)f0.y;
  t_lds[n0 +  2][kk] = (_Float16)f0.z; t_lds[n0 +  3][kk] = (_Float16)f0.w;
  t_lds[n0 +  4][kk] = (_Float16)f1.x; t_lds[n0 +  5][kk] = (_Float16)f1.y;
  t_lds[n0 +  6][kk] = (_Float16)f1.z; t_lds[n0 +  7][kk] = (_Float16)f1.w;
  t_lds[n0 +  8][kk] = (_Float16)f2.x; t_lds[n0 +  9][kk] = (_Float16)f2.y;
  t_lds[n0 + 10][kk] = (_Float16)f2.z; t_lds[n0 + 11][kk] = (_Float16)f2.w;
  t_lds[n0 + 12][kk] = (_Float16)f3.x; t_lds[n0 + 13][kk] = (_Float16)f3.y;
  t_lds[n0 + 14][kk] = (_Float16)f3.z; t_lds[n0 + 15][kk] = (_Float16)f3.w;
  __syncthreads();
  const int n = tid >> 2;
  const int koff = (tid & 3) * 16;
  half8 h0 = *(const half8*)&t_lds[n][koff];
  half8 h1 = *(const half8*)&t_lds[n][koff + 8];
  _Float16* dst = Wt + (size_t)(w * 64 + n) * 512 + kb * 64 + koff;
  *(half8*)dst = h0;
  *(half8*)(dst + 8) = h1;
}

// ---- Projection: out[m][n] = sum_k X[m][k] W[k][n]. M=65536 (128/block), K=512, N=64.
// Barrier-free, LDS-free main loop: A frags direct from global (each row read once,
// no cross-wave reuse), B frags direct from L1/L2-hot Wt (f16, pre-transposed).
// NOUT=1: q (normal layout). NOUT=2: k (normal) + v (TRANSPOSED [b][h][t] via LDS tile).
template <int NOUT>
__global__ __launch_bounds__(256, 2) void proj_kernel(
    const float* __restrict__ X, const _Float16* __restrict__ Wt0,
    const _Float16* __restrict__ Wt1, _Float16* __restrict__ O0,
    _Float16* __restrict__ O1t) {
  __shared__ _Float16 vt_tile[NOUT == 2 ? 64 : 1][NOUT == 2 ? 136 : 1];  // [h][t], 272B rows

  const int tid = threadIdx.x;
  const int row0 = blockIdx.x * 128;
  const int wv = tid >> 6;
  const int lane = tid & 63;
  const int l15 = lane & 15, quad = lane >> 4;

  floatx4 acc[2][4 * NOUT];
#pragma unroll
  for (int i = 0; i < 2; i++)
#pragma unroll
    for (int j = 0; j < 4 * NOUT; j++) acc[i][j] = (floatx4)0.f;

  const float* xr0 = X + (size_t)(row0 + wv * 32 + l15) * 512 + quad * 8;
  const float* xr1 = xr0 + 16 * 512;

#pragma unroll
  for (int k0 = 0; k0 < 512; k0 += 32) {
    float4 a0 = *(const float4*)(xr0 + k0);
    float4 a1 = *(const float4*)(xr0 + k0 + 4);
    float4 a2 = *(const float4*)(xr1 + k0);
    float4 a3 = *(const float4*)(xr1 + k0 + 4);
    half8 af0 = cvt8(a0, a1);
    half8 af1 = cvt8(a2, a3);
#pragma unroll
    for (int wi = 0; wi < NOUT; wi++) {
      const _Float16* wp = (wi ? Wt1 : Wt0) + k0 + quad * 8;
#pragma unroll
      for (int j = 0; j < 4; j++) {
        half8 bf = *(const half8*)(wp + (size_t)(j * 16 + l15) * 512);
        acc[0][wi * 4 + j] = MFMA16(af0, bf, acc[0][wi * 4 + j]);
        acc[1][wi * 4 + j] = MFMA16(af1, bf, acc[1][wi * 4 + j]);
      }
    }
  }

  // epilogue: C/D layout col=l15, row=quad*4+r. q/k direct scalar stores.
#pragma unroll
  for (int i = 0; i < 2; i++)
#pragma unroll
    for (int j = 0; j < 4; j++)
#pragma unroll
      for (int r = 0; r < 4; r++) {
        int grow = row0 + wv * 32 + i * 16 + quad * 4 + r;
        O0[(size_t)grow * 64 + j * 16 + l15] = (_Float16)acc[i][j][r];
      }
  if constexpr (NOUT == 2) {
    // V: transpose in LDS, store coalesced to Vt[b][h][t]
#pragma unroll
    for (int i = 0; i < 2; i++)
#pragma unroll
      for (int j = 0; j < 4; j++)
#pragma unroll
        for (int r = 0; r < 4; r++) {
          int tl = wv * 32 + i * 16 + quad * 4 + r;
          vt_tile[j * 16 + l15][tl] = (_Float16)acc[i][4 + j][r];
        }
    __syncthreads();
    const int b = row0 >> 8, t0 = row0 & 255;
    const int h = tid >> 2;
    const int seg = (tid & 3) * 32;
    _Float16* dst = O1t + ((size_t)b * 64 + h) * 256 + t0 + seg;
#pragma unroll
    for (int e = 0; e < 4; e++)
      *(half8*)(dst + e * 8) = *(const half8*)&vt_tile[h][seg + e * 8];
  }
}

// ---- Flash attention, causal. Grid (qt=4, b=256); block 256 = 4 waves x 16 q-rows.
// Zero barriers: K and V^T fragments read directly from global (L1-hot, 4-wave reuse);
// p_lds is wave-private (within-wave RAW handled by lgkmcnt).
__global__ __launch_bounds__(256) void attn_kernel(
    const _Float16* __restrict__ Qw, const _Float16* __restrict__ Kw,
    const _Float16* __restrict__ Vt, float* __restrict__ Out) {
  __shared__ _Float16 p_lds[4][16][72];  // per-wave P round-trip

  const int qt = blockIdx.x, bb = blockIdx.y;
  const int tid = threadIdx.x;
  const int wv = tid >> 6;
  const int lane = tid & 63;
  const int l15 = lane & 15, quad = lane >> 4;
  const float SCALE = 0.125f * 1.4426950408889634f;  // (1/sqrt(64)) * log2(e)
  const float NEG = -3.0e38f;

  const size_t qoff = ((size_t)bb * 256 + qt * 64 + wv * 16 + l15) * 64 + quad * 8;
  half8 qf0 = *(const half8*)(Qw + qoff);
  half8 qf1 = *(const half8*)(Qw + qoff + 32);

  floatx4 o[4];
#pragma unroll
  for (int t = 0; t < 4; t++) o[t] = (floatx4)0.f;
  float mrow[4], lrow[4];
#pragma unroll
  for (int r = 0; r < 4; r++) { mrow[r] = NEG; lrow[r] = 0.f; }

  const _Float16* Kb = Kw + (size_t)bb * 256 * 64;
  const _Float16* Vb = Vt + (size_t)bb * 64 * 256;

  for (int j = 0; j <= qt; j++) {
    // S = Q K^T : K frags direct from global ([s][h] layout is B-layout-native)
    floatx4 sacc[4];
#pragma unroll
    for (int t = 0; t < 4; t++) sacc[t] = (floatx4)0.f;
#pragma unroll
    for (int t = 0; t < 4; t++) {
      const _Float16* kp = Kb + (size_t)(j * 64 + t * 16 + l15) * 64 + quad * 8;
      half8 b0 = *(const half8*)kp;
      half8 b1 = *(const half8*)(kp + 32);
      sacc[t] = MFMA16(qf0, b0, sacc[t]);
      sacc[t] = MFMA16(qf1, b1, sacc[t]);
    }

    // V^T frags prefetched now; latency hides under softmax VALU
    half8 vb[2][4];
#pragma unroll
    for (int ss = 0; ss < 2; ss++)
#pragma unroll
      for (int th = 0; th < 4; th++)
        vb[ss][th] = *(const half8*)(Vb + (size_t)(th * 16 + l15) * 256 +
                                     j * 64 + ss * 32 + quad * 8);

    // scale + causal mask (C/D layout: col = t*16+l15, row = quad*4+r)
    float y[4][4];
#pragma unroll
    for (int t = 0; t < 4; t++)
#pragma unroll
      for (int r = 0; r < 4; r++) y[t][r] = sacc[t][r] * SCALE;
    if (j == qt) {
#pragma unroll
      for (int t = 0; t < 4; t++)
#pragma unroll
        for (int r = 0; r < 4; r++)
          if (t * 16 + l15 > wv * 16 + quad * 4 + r) y[t][r] = NEG;
    }

    // online softmax per q-row (reduce across the quad's 16 lanes)
#pragma unroll
    for (int r = 0; r < 4; r++) {
      float mx = fmaxf(fmaxf(y[0][r], y[1][r]), fmaxf(y[2][r], y[3][r]));
#pragma unroll
      for (int off = 1; off < 16; off <<= 1) mx = fmaxf(mx, __shfl_xor(mx, off, 64));
      float mnew = fmaxf(mrow[r], mx);
      float al = exp2f(mrow[r] - mnew);
      mrow[r] = mnew;
      float rs = 0.f;
#pragma unroll
      for (int t = 0; t < 4; t++) {
        float p = exp2f(y[t][r] - mnew);
        y[t][r] = p;
        rs += p;
      }
#pragma unroll
      for (int off = 1; off < 16; off <<= 1) rs += __shfl_xor(rs, off, 64);
      lrow[r] = lrow[r] * al + rs;
      o[0][r] *= al; o[1][r] *= al; o[2][r] *= al; o[3][r] *= al;
    }

    // P: C/D layout -> wave-private LDS -> A layout (no barrier needed)
#pragma unroll
    for (int t = 0; t < 4; t++)
#pragma unroll
      for (int r = 0; r < 4; r++)
        p_lds[wv][quad * 4 + r][t * 16 + l15] = (_Float16)y[t][r];

    // O += P V
#pragma unroll
    for (int ss = 0; ss < 2; ss++) {
      half8 pa = *(const half8*)&p_lds[wv][l15][ss * 32 + quad * 8];
#pragma unroll
      for (int th = 0; th < 4; th++) o[th] = MFMA16(pa, vb[ss][th], o[th]);
    }
  }

  // normalize + store fp32
#pragma unroll
  for (int th = 0; th < 4; th++)
#pragma unroll
    for (int r = 0; r < 4; r++) {
      int grow = qt * 64 + wv * 16 + quad * 4 + r;
      Out[((size_t)bb * 256 + grow) * 64 + th * 16 + l15] = o[th][r] / lrow[r];
    }
}

extern "C" void kernel_launch(void* const* d_in, const int* in_sizes, int n_in,
                              void* d_out, int out_size, void* d_ws, size_t ws_size,
                              hipStream_t stream) {
  const float* x  = (const float*)d_in[0];
  const float* y  = (const float*)d_in[1];
  const float* Wq = (const float*)d_in[2];
  const float* Wk = (const float*)d_in[3];
  const float* Wv = (const float*)d_in[4];
  float* out = (float*)d_out;

  _Float16* qw = (_Float16*)d_ws;
  _Float16* kw = qw + (size_t)65536 * 64;
  _Float16* vt = kw + (size_t)65536 * 64;
  _Float16* wt = vt + (size_t)65536 * 64;  // [3][64][512]

  wt_kernel<<<24, 256, 0, stream>>>(Wq, Wk, Wv, wt);
  proj_kernel<1><<<512, 256, 0, stream>>>(x, wt, nullptr, qw, nullptr);
  proj_kernel<2><<<512, 256, 0, stream>>>(y, wt + (size_t)64 * 512,
                                          wt + (size_t)2 * 64 * 512, kw, vt);
  attn_kernel<<<dim3(4, 256), 256, 0, stream>>>(qw, kw, vt, out);
}

// Round 8
// 328.836 us; speedup vs baseline: 1.0621x; 1.0621x over previous
//
#include <hip/hip_runtime.h>

// B=256, T=256, C=512, H=64. fp32 in; f16 MFMA w/ fp32 acc.
// ws: qw (65536x64 f16) | kw | vt ([256][64][256] f16, V transposed)
// proj = known-good round-0 staged structure (isolates attn as the single variable).

typedef _Float16 half8 __attribute__((ext_vector_type(8)));
typedef float floatx4 __attribute__((ext_vector_type(4)));

#define MFMA16(a, b, c) __builtin_amdgcn_mfma_f32_16x16x32_f16((a), (b), (c), 0, 0, 0)

__device__ inline half8 cvt8(float4 a, float4 b) {
  half8 r;
  r[0] = (_Float16)a.x; r[1] = (_Float16)a.y; r[2] = (_Float16)a.z; r[3] = (_Float16)a.w;
  r[4] = (_Float16)b.x; r[5] = (_Float16)b.y; r[6] = (_Float16)b.z; r[7] = (_Float16)b.w;
  return r;
}

// GEMM: out[m][n] = sum_k X[m][k] * W[k][n], M=65536 (128/block), K=512, N=64.
// NOUT=1: q = x*Wq (normal layout). NOUT=2: k = y*Wk (normal) + v = y*Wv (TRANSPOSED [b][h][t]).
template <int NOUT>
__global__ __launch_bounds__(256) void proj_kernel(
    const float* __restrict__ X, const float* __restrict__ W0,
    const float* __restrict__ W1, _Float16* __restrict__ O0,
    _Float16* __restrict__ O1t) {
  __shared__ _Float16 a_lds[128][40];        // 128 rows x 32 k, pad->40 (2-way ok)
  __shared__ _Float16 w_lds[NOUT][64][40];   // W^T: [n][k], pad->40
  __shared__ _Float16 vt_tile[NOUT == 2 ? 64 : 1][NOUT == 2 ? 136 : 1];  // [h][t]

  const int tid = threadIdx.x;
  const int row0 = blockIdx.x * 128;
  const int wv = tid >> 6;
  const int lane = tid & 63;
  const int l15 = lane & 15, quad = lane >> 4;

  floatx4 acc[2][4 * NOUT];
#pragma unroll
  for (int i = 0; i < 2; i++)
#pragma unroll
    for (int j = 0; j < 4 * NOUT; j++) acc[i][j] = (floatx4)0.f;

  const int arow = tid >> 1;            // 0..127
  const int ahalf = (tid & 1) * 16;     // 0 or 16 (k-cols)
  const int wkk = tid >> 3;             // 0..31 (k row of W)
  const int wn0 = (tid & 7) * 8;        // 0..56 (n col of W)

  for (int k0 = 0; k0 < 512; k0 += 32) {
    // ---- stage A tile (128 x 32), fp32 -> f16 ----
    {
      const float4* s4 = (const float4*)(X + (size_t)(row0 + arow) * 512 + k0 + ahalf);
      float4 f0 = s4[0], f1 = s4[1], f2 = s4[2], f3 = s4[3];
      *(half8*)&a_lds[arow][ahalf]     = cvt8(f0, f1);
      *(half8*)&a_lds[arow][ahalf + 8] = cvt8(f2, f3);
    }
    // ---- stage W^T tile(s) (64 n x 32 k), transposed scalar writes ----
#pragma unroll
    for (int wi = 0; wi < NOUT; wi++) {
      const float* wsrc = (wi ? W1 : W0) + (size_t)(k0 + wkk) * 64 + wn0;
      float4 g0 = ((const float4*)wsrc)[0];
      float4 g1 = ((const float4*)wsrc)[1];
      w_lds[wi][wn0 + 0][wkk] = (_Float16)g0.x;
      w_lds[wi][wn0 + 1][wkk] = (_Float16)g0.y;
      w_lds[wi][wn0 + 2][wkk] = (_Float16)g0.z;
      w_lds[wi][wn0 + 3][wkk] = (_Float16)g0.w;
      w_lds[wi][wn0 + 4][wkk] = (_Float16)g1.x;
      w_lds[wi][wn0 + 5][wkk] = (_Float16)g1.y;
      w_lds[wi][wn0 + 6][wkk] = (_Float16)g1.z;
      w_lds[wi][wn0 + 7][wkk] = (_Float16)g1.w;
    }
    __syncthreads();
    // ---- MFMA: each wave does 32 rows x (64*NOUT) cols ----
    half8 af0 = *(const half8*)&a_lds[wv * 32 + l15][quad * 8];
    half8 af1 = *(const half8*)&a_lds[wv * 32 + 16 + l15][quad * 8];
#pragma unroll
    for (int wi = 0; wi < NOUT; wi++)
#pragma unroll
      for (int j = 0; j < 4; j++) {
        half8 bf = *(const half8*)&w_lds[wi][j * 16 + l15][quad * 8];
        acc[0][wi * 4 + j] = MFMA16(af0, bf, acc[0][wi * 4 + j]);
        acc[1][wi * 4 + j] = MFMA16(af1, bf, acc[1][wi * 4 + j]);
      }
    __syncthreads();
  }
  // ---- epilogue: C/D layout col=l15, row=quad*4+r ----
  // q/k (wi=0): direct stores, normal [t][h] layout
#pragma unroll
  for (int i = 0; i < 2; i++)
#pragma unroll
    for (int j = 0; j < 4; j++)
#pragma unroll
      for (int r = 0; r < 4; r++) {
        int grow = row0 + wv * 32 + i * 16 + quad * 4 + r;
        O0[(size_t)grow * 64 + j * 16 + l15] = (_Float16)acc[i][j][r];
      }
  if constexpr (NOUT == 2) {
    // v (wi=1): transpose in LDS, store coalesced to Vt[b][h][t]
#pragma unroll
    for (int i = 0; i < 2; i++)
#pragma unroll
      for (int j = 0; j < 4; j++)
#pragma unroll
        for (int r = 0; r < 4; r++) {
          int tl = wv * 32 + i * 16 + quad * 4 + r;
          vt_tile[j * 16 + l15][tl] = (_Float16)acc[i][4 + j][r];
        }
    __syncthreads();
    const int b = row0 >> 8, t0 = row0 & 255;
    const int h = tid >> 2;
    const int seg = (tid & 3) * 32;
    _Float16* dst = O1t + ((size_t)b * 64 + h) * 256 + t0 + seg;
#pragma unroll
    for (int e = 0; e < 4; e++)
      *(half8*)(dst + e * 8) = *(const half8*)&vt_tile[h][seg + e * 8];
  }
}

// ---- Flash attention, causal. Grid (qt=4, b=256); block 256 = 4 waves x 16 q-rows.
// Zero barriers: K and V^T fragments read directly from global (L1-hot, 16-wave reuse
// per tile); p_lds is wave-private (within-wave RAW handled by lgkmcnt).
__global__ __launch_bounds__(256) void attn_kernel(
    const _Float16* __restrict__ Qw, const _Float16* __restrict__ Kw,
    const _Float16* __restrict__ Vt, float* __restrict__ Out) {
  __shared__ _Float16 p_lds[4][16][72];  // per-wave P round-trip

  const int qt = blockIdx.x, bb = blockIdx.y;
  const int tid = threadIdx.x;
  const int wv = tid >> 6;
  const int lane = tid & 63;
  const int l15 = lane & 15, quad = lane >> 4;
  const float SCALE = 0.125f * 1.4426950408889634f;  // (1/sqrt(64)) * log2(e)
  const float NEG = -3.0e38f;

  const size_t qoff = ((size_t)bb * 256 + qt * 64 + wv * 16 + l15) * 64 + quad * 8;
  half8 qf0 = *(const half8*)(Qw + qoff);
  half8 qf1 = *(const half8*)(Qw + qoff + 32);

  floatx4 o[4];
#pragma unroll
  for (int t = 0; t < 4; t++) o[t] = (floatx4)0.f;
  float mrow[4], lrow[4];
#pragma unroll
  for (int r = 0; r < 4; r++) { mrow[r] = NEG; lrow[r] = 0.f; }

  const _Float16* Kb = Kw + (size_t)bb * 256 * 64;
  const _Float16* Vb = Vt + (size_t)bb * 64 * 256;

  for (int j = 0; j <= qt; j++) {
    // S = Q K^T : K frags direct from global ([s][h] layout is B-layout-native)
    floatx4 sacc[4];
#pragma unroll
    for (int t = 0; t < 4; t++) sacc[t] = (floatx4)0.f;
#pragma unroll
    for (int t = 0; t < 4; t++) {
      const _Float16* kp = Kb + (size_t)(j * 64 + t * 16 + l15) * 64 + quad * 8;
      half8 b0 = *(const half8*)kp;
      half8 b1 = *(const half8*)(kp + 32);
      sacc[t] = MFMA16(qf0, b0, sacc[t]);
      sacc[t] = MFMA16(qf1, b1, sacc[t]);
    }

    // V^T frags prefetched now; latency hides under softmax VALU
    half8 vb[2][4];
#pragma unroll
    for (int ss = 0; ss < 2; ss++)
#pragma unroll
      for (int th = 0; th < 4; th++)
        vb[ss][th] = *(const half8*)(Vb + (size_t)(th * 16 + l15) * 256 +
                                     j * 64 + ss * 32 + quad * 8);

    // scale + causal mask (C/D layout: col = t*16+l15, row = quad*4+r)
    float y[4][4];
#pragma unroll
    for (int t = 0; t < 4; t++)
#pragma unroll
      for (int r = 0; r < 4; r++) y[t][r] = sacc[t][r] * SCALE;
    if (j == qt) {
#pragma unroll
      for (int t = 0; t < 4; t++)
#pragma unroll
        for (int r = 0; r < 4; r++)
          if (t * 16 + l15 > wv * 16 + quad * 4 + r) y[t][r] = NEG;
    }

    // online softmax per q-row (reduce across the quad's 16 lanes)
#pragma unroll
    for (int r = 0; r < 4; r++) {
      float mx = fmaxf(fmaxf(y[0][r], y[1][r]), fmaxf(y[2][r], y[3][r]));
#pragma unroll
      for (int off = 1; off < 16; off <<= 1) mx = fmaxf(mx, __shfl_xor(mx, off, 64));
      float mnew = fmaxf(mrow[r], mx);
      float al = exp2f(mrow[r] - mnew);
      mrow[r] = mnew;
      float rs = 0.f;
#pragma unroll
      for (int t = 0; t < 4; t++) {
        float p = exp2f(y[t][r] - mnew);
        y[t][r] = p;
        rs += p;
      }
#pragma unroll
      for (int off = 1; off < 16; off <<= 1) rs += __shfl_xor(rs, off, 64);
      lrow[r] = lrow[r] * al + rs;
      o[0][r] *= al; o[1][r] *= al; o[2][r] *= al; o[3][r] *= al;
    }

    // P: C/D layout -> wave-private LDS -> A layout (no barrier needed)
#pragma unroll
    for (int t = 0; t < 4; t++)
#pragma unroll
      for (int r = 0; r < 4; r++)
        p_lds[wv][quad * 4 + r][t * 16 + l15] = (_Float16)y[t][r];

    // O += P V
#pragma unroll
    for (int ss = 0; ss < 2; ss++) {
      half8 pa = *(const half8*)&p_lds[wv][l15][ss * 32 + quad * 8];
#pragma unroll
      for (int th = 0; th < 4; th++) o[th] = MFMA16(pa, vb[ss][th], o[th]);
    }
  }

  // normalize + store fp32
#pragma unroll
  for (int th = 0; th < 4; th++)
#pragma unroll
    for (int r = 0; r < 4; r++) {
      int grow = qt * 64 + wv * 16 + quad * 4 + r;
      Out[((size_t)bb * 256 + grow) * 64 + th * 16 + l15] = o[th][r] / lrow[r];
    }
}

extern "C" void kernel_launch(void* const* d_in, const int* in_sizes, int n_in,
                              void* d_out, int out_size, void* d_ws, size_t ws_size,
                              hipStream_t stream) {
  const float* x  = (const float*)d_in[0];
  const float* y  = (const float*)d_in[1];
  const float* Wq = (const float*)d_in[2];
  const float* Wk = (const float*)d_in[3];
  const float* Wv = (const float*)d_in[4];
  float* out = (float*)d_out;

  _Float16* qw = (_Float16*)d_ws;
  _Float16* kw = qw + (size_t)65536 * 64;
  _Float16* vt = kw + (size_t)65536 * 64;  // [256][64][256]

  proj_kernel<1><<<512, 256, 0, stream>>>(x, Wq, nullptr, qw, nullptr);
  proj_kernel<2><<<512, 256, 0, stream>>>(y, Wk, Wv, kw, vt);
  attn_kernel<<<dim3(4, 256), 256, 0, stream>>>(qw, kw, vt, out);
}

// Round 15
// 318.052 us; speedup vs baseline: 1.0981x; 1.0339x over previous
//
#include <hip/hip_runtime.h>

// B=256, T=256, C=512, H=64. fp32 in; f16 MFMA w/ fp32 acc.
// ws: qw (65536x64 f16) | kw | vt ([256][64][256] f16, V transposed)
// proj: R8 known-good (staged, Vt epilogue). attn: hybrid (LDS-staged K/Vt,
// coalesced stage from pre-transposed Vt, 2 barriers/iter, T14 prefetch).

typedef _Float16 half8 __attribute__((ext_vector_type(8)));
typedef float floatx4 __attribute__((ext_vector_type(4)));

#define MFMA16(a, b, c) __builtin_amdgcn_mfma_f32_16x16x32_f16((a), (b), (c), 0, 0, 0)

__device__ inline half8 cvt8(float4 a, float4 b) {
  half8 r;
  r[0] = (_Float16)a.x; r[1] = (_Float16)a.y; r[2] = (_Float16)a.z; r[3] = (_Float16)a.w;
  r[4] = (_Float16)b.x; r[5] = (_Float16)b.y; r[6] = (_Float16)b.z; r[7] = (_Float16)b.w;
  return r;
}

// GEMM: out[m][n] = sum_k X[m][k] * W[k][n], M=65536 (128/block), K=512, N=64.
// NOUT=1: q = x*Wq (normal layout). NOUT=2: k = y*Wk (normal) + v = y*Wv (TRANSPOSED [b][h][t]).
template <int NOUT>
__global__ __launch_bounds__(256) void proj_kernel(
    const float* __restrict__ X, const float* __restrict__ W0,
    const float* __restrict__ W1, _Float16* __restrict__ O0,
    _Float16* __restrict__ O1t) {
  __shared__ _Float16 a_lds[128][40];        // 128 rows x 32 k, pad->40 (2-way ok)
  __shared__ _Float16 w_lds[NOUT][64][40];   // W^T: [n][k], pad->40
  __shared__ _Float16 vt_tile[NOUT == 2 ? 64 : 1][NOUT == 2 ? 136 : 1];  // [h][t]

  const int tid = threadIdx.x;
  const int row0 = blockIdx.x * 128;
  const int wv = tid >> 6;
  const int lane = tid & 63;
  const int l15 = lane & 15, quad = lane >> 4;

  floatx4 acc[2][4 * NOUT];
#pragma unroll
  for (int i = 0; i < 2; i++)
#pragma unroll
    for (int j = 0; j < 4 * NOUT; j++) acc[i][j] = (floatx4)0.f;

  const int arow = tid >> 1;            // 0..127
  const int ahalf = (tid & 1) * 16;     // 0 or 16 (k-cols)
  const int wkk = tid >> 3;             // 0..31 (k row of W)
  const int wn0 = (tid & 7) * 8;        // 0..56 (n col of W)

  for (int k0 = 0; k0 < 512; k0 += 32) {
    // ---- stage A tile (128 x 32), fp32 -> f16 ----
    {
      const float4* s4 = (const float4*)(X + (size_t)(row0 + arow) * 512 + k0 + ahalf);
      float4 f0 = s4[0], f1 = s4[1], f2 = s4[2], f3 = s4[3];
      *(half8*)&a_lds[arow][ahalf]     = cvt8(f0, f1);
      *(half8*)&a_lds[arow][ahalf + 8] = cvt8(f2, f3);
    }
    // ---- stage W^T tile(s) (64 n x 32 k), transposed scalar writes ----
#pragma unroll
    for (int wi = 0; wi < NOUT; wi++) {
      const float* wsrc = (wi ? W1 : W0) + (size_t)(k0 + wkk) * 64 + wn0;
      float4 g0 = ((const float4*)wsrc)[0];
      float4 g1 = ((const float4*)wsrc)[1];
      w_lds[wi][wn0 + 0][wkk] = (_Float16)g0.x;
      w_lds[wi][wn0 + 1][wkk] = (_Float16)g0.y;
      w_lds[wi][wn0 + 2][wkk] = (_Float16)g0.z;
      w_lds[wi][wn0 + 3][wkk] = (_Float16)g0.w;
      w_lds[wi][wn0 + 4][wkk] = (_Float16)g1.x;
      w_lds[wi][wn0 + 5][wkk] = (_Float16)g1.y;
      w_lds[wi][wn0 + 6][wkk] = (_Float16)g1.z;
      w_lds[wi][wn0 + 7][wkk] = (_Float16)g1.w;
    }
    __syncthreads();
    // ---- MFMA: each wave does 32 rows x (64*NOUT) cols ----
    half8 af0 = *(const half8*)&a_lds[wv * 32 + l15][quad * 8];
    half8 af1 = *(const half8*)&a_lds[wv * 32 + 16 + l15][quad * 8];
#pragma unroll
    for (int wi = 0; wi < NOUT; wi++)
#pragma unroll
      for (int j = 0; j < 4; j++) {
        half8 bf = *(const half8*)&w_lds[wi][j * 16 + l15][quad * 8];
        acc[0][wi * 4 + j] = MFMA16(af0, bf, acc[0][wi * 4 + j]);
        acc[1][wi * 4 + j] = MFMA16(af1, bf, acc[1][wi * 4 + j]);
      }
    __syncthreads();
  }
  // ---- epilogue: C/D layout col=l15, row=quad*4+r ----
#pragma unroll
  for (int i = 0; i < 2; i++)
#pragma unroll
    for (int j = 0; j < 4; j++)
#pragma unroll
      for (int r = 0; r < 4; r++) {
        int grow = row0 + wv * 32 + i * 16 + quad * 4 + r;
        O0[(size_t)grow * 64 + j * 16 + l15] = (_Float16)acc[i][j][r];
      }
  if constexpr (NOUT == 2) {
    // v (wi=1): transpose in LDS, store coalesced to Vt[b][h][t]
#pragma unroll
    for (int i = 0; i < 2; i++)
#pragma unroll
      for (int j = 0; j < 4; j++)
#pragma unroll
        for (int r = 0; r < 4; r++) {
          int tl = wv * 32 + i * 16 + quad * 4 + r;
          vt_tile[j * 16 + l15][tl] = (_Float16)acc[i][4 + j][r];
        }
    __syncthreads();
    const int b = row0 >> 8, t0 = row0 & 255;
    const int h = tid >> 2;
    const int seg = (tid & 3) * 32;
    _Float16* dst = O1t + ((size_t)b * 64 + h) * 256 + t0 + seg;
#pragma unroll
    for (int e = 0; e < 4; e++)
      *(half8*)(dst + e * 8) = *(const half8*)&vt_tile[h][seg + e * 8];
  }
}

// ---- Flash attention, causal. Grid (qt=4, b=256); block 256 = 4 waves x 16 q-rows.
// Hybrid: K and Vt staged in LDS (coalesced both sides; Vt pre-transposed by proj),
// 2 barriers/iter, T14 prefetch (j+1 loads issued under j's compute).
__global__ __launch_bounds__(256) void attn_kernel(
    const _Float16* __restrict__ Qw, const _Float16* __restrict__ Kw,
    const _Float16* __restrict__ Vt, float* __restrict__ Out) {
  __shared__ _Float16 k_lds[64][72];       // [s][h]
  __shared__ _Float16 vt_lds[64][72];      // [h][s]
  __shared__ _Float16 p_lds[4][16][72];    // per-wave P round-trip (wave-private)

  const int qt = blockIdx.x, bb = blockIdx.y;
  const int tid = threadIdx.x;
  const int wv = tid >> 6;
  const int lane = tid & 63;
  const int l15 = lane & 15, quad = lane >> 4;
  const float SCALE = 0.125f * 1.4426950408889634f;  // (1/sqrt(64)) * log2(e)
  const float NEG = -3.0e38f;

  const size_t qoff = ((size_t)bb * 256 + qt * 64 + wv * 16 + l15) * 64 + quad * 8;
  half8 qf0 = *(const half8*)(Qw + qoff);
  half8 qf1 = *(const half8*)(Qw + qoff + 32);

  floatx4 o[4];
#pragma unroll
  for (int t = 0; t < 4; t++) o[t] = (floatx4)0.f;
  float mrow[4], lrow[4];
#pragma unroll
  for (int r = 0; r < 4; r++) { mrow[r] = NEG; lrow[r] = 0.f; }

  const _Float16* Kb = Kw + (size_t)bb * 256 * 64;   // [t][h]
  const _Float16* Vb = Vt + (size_t)bb * 64 * 256;   // [h][t]

  const int srow = tid >> 2;          // 0..63
  const int sc = (tid & 3) * 16;      // 0,16,32,48

  // T14 prologue: issue j=0 K/Vt loads
  half8 kr0, kr1, vr0, vr1;
  {
    const half8* kp = (const half8*)(Kb + (size_t)srow * 64 + sc);
    kr0 = kp[0]; kr1 = kp[1];
    const half8* vp = (const half8*)(Vb + (size_t)srow * 256 + sc);
    vr0 = vp[0]; vr1 = vp[1];
  }

  for (int j = 0; j <= qt; j++) {
    // write staged regs -> LDS (coalesced, no transpose)
    *(half8*)&k_lds[srow][sc]      = kr0;
    *(half8*)&k_lds[srow][sc + 8]  = kr1;
    *(half8*)&vt_lds[srow][sc]     = vr0;
    *(half8*)&vt_lds[srow][sc + 8] = vr1;
    __syncthreads();

    // T14: issue j+1 loads now; latency hides under QK^T/softmax/PV
    if (j < qt) {
      const half8* kp = (const half8*)(Kb + (size_t)((j + 1) * 64 + srow) * 64 + sc);
      kr0 = kp[0]; kr1 = kp[1];
      const half8* vp = (const half8*)(Vb + (size_t)srow * 256 + (j + 1) * 64 + sc);
      vr0 = vp[0]; vr1 = vp[1];
    }

    // S = Q K^T : 16 q-rows x 64 s-cols per wave
    floatx4 sacc[4];
#pragma unroll
    for (int t = 0; t < 4; t++) sacc[t] = (floatx4)0.f;
#pragma unroll
    for (int t = 0; t < 4; t++) {
      half8 b0 = *(const half8*)&k_lds[t * 16 + l15][quad * 8];
      sacc[t] = MFMA16(qf0, b0, sacc[t]);
      half8 b1 = *(const half8*)&k_lds[t * 16 + l15][32 + quad * 8];
      sacc[t] = MFMA16(qf1, b1, sacc[t]);
    }

    // scale + causal mask (C/D layout: col = t*16+l15, row = quad*4+r)
    float y[4][4];
#pragma unroll
    for (int t = 0; t < 4; t++)
#pragma unroll
      for (int r = 0; r < 4; r++) y[t][r] = sacc[t][r] * SCALE;
    if (j == qt) {
#pragma unroll
      for (int t = 0; t < 4; t++)
#pragma unroll
        for (int r = 0; r < 4; r++)
          if (t * 16 + l15 > wv * 16 + quad * 4 + r) y[t][r] = NEG;
    }

    // online softmax per q-row (reduce across the quad's 16 lanes)
#pragma unroll
    for (int r = 0; r < 4; r++) {
      float mx = fmaxf(fmaxf(y[0][r], y[1][r]), fmaxf(y[2][r], y[3][r]));
#pragma unroll
      for (int off = 1; off < 16; off <<= 1) mx = fmaxf(mx, __shfl_xor(mx, off, 64));
      float mnew = fmaxf(mrow[r], mx);
      float al = exp2f(mrow[r] - mnew);
      mrow[r] = mnew;
      float rs = 0.f;
#pragma unroll
      for (int t = 0; t < 4; t++) {
        float p = exp2f(y[t][r] - mnew);
        y[t][r] = p;
        rs += p;
      }
#pragma unroll
      for (int off = 1; off < 16; off <<= 1) rs += __shfl_xor(rs, off, 64);
      lrow[r] = lrow[r] * al + rs;
      o[0][r] *= al; o[1][r] *= al; o[2][r] *= al; o[3][r] *= al;
    }

    // P: C/D layout -> wave-private LDS -> A layout (no barrier needed)
#pragma unroll
    for (int t = 0; t < 4; t++)
#pragma unroll
      for (int r = 0; r < 4; r++)
        p_lds[wv][quad * 4 + r][t * 16 + l15] = (_Float16)y[t][r];

    // O += P V
#pragma unroll
    for (int ss = 0; ss < 2; ss++) {
      half8 pa = *(const half8*)&p_lds[wv][l15][ss * 32 + quad * 8];
#pragma unroll
      for (int th = 0; th < 4; th++) {
        half8 vbf = *(const half8*)&vt_lds[th * 16 + l15][ss * 32 + quad * 8];
        o[th] = MFMA16(pa, vbf, o[th]);
      }
    }
    __syncthreads();  // all waves done reading k_lds/vt_lds before next overwrite
  }

  // normalize + store fp32
#pragma unroll
  for (int th = 0; th < 4; th++)
#pragma unroll
    for (int r = 0; r < 4; r++) {
      int grow = qt * 64 + wv * 16 + quad * 4 + r;
      Out[((size_t)bb * 256 + grow) * 64 + th * 16 + l15] = o[th][r] / lrow[r];
    }
}

extern "C" void kernel_launch(void* const* d_in, const int* in_sizes, int n_in,
                              void* d_out, int out_size, void* d_ws, size_t ws_size,
                              hipStream_t stream) {
  const float* x  = (const float*)d_in[0];
  const float* y  = (const float*)d_in[1];
  const float* Wq = (const float*)d_in[2];
  const float* Wk = (const float*)d_in[3];
  const float* Wv = (const float*)d_in[4];
  float* out = (float*)d_out;

  _Float16* qw = (_Float16*)d_ws;
  _Float16* kw = qw + (size_t)65536 * 64;
  _Float16* vt = kw + (size_t)65536 * 64;  // [256][64][256]

  proj_kernel<1><<<512, 256, 0, stream>>>(x, Wq, nullptr, qw, nullptr);
  proj_kernel<2><<<512, 256, 0, stream>>>(y, Wk, Wv, kw, vt);
  attn_kernel<<<dim3(4, 256), 256, 0, stream>>>(qw, kw, vt, out);
}

// Round 16
// 317.034 us; speedup vs baseline: 1.1016x; 1.0032x over previous
//
#include <hip/hip_runtime.h>

// B=256, T=256, C=512, H=64. fp32 in; f16 MFMA w/ fp32 acc.
// ws: qw (65536x64 f16) | kw | vt ([256][64][256] f16) | wt ([3][64][512] f16)
// R15 structure; single change: W staged from precomputed global Wt (f16, transposed)
// via vectorized LDS writes instead of per-block scalar transposed writes.

typedef _Float16 half8 __attribute__((ext_vector_type(8)));
typedef float floatx4 __attribute__((ext_vector_type(4)));

#define MFMA16(a, b, c) __builtin_amdgcn_mfma_f32_16x16x32_f16((a), (b), (c), 0, 0, 0)

__device__ inline half8 cvt8(float4 a, float4 b) {
  half8 r;
  r[0] = (_Float16)a.x; r[1] = (_Float16)a.y; r[2] = (_Float16)a.z; r[3] = (_Float16)a.w;
  r[4] = (_Float16)b.x; r[5] = (_Float16)b.y; r[6] = (_Float16)b.z; r[7] = (_Float16)b.w;
  return r;
}

// ---- W transpose: W[512][64] f32 -> Wt[w][64][512] f16. grid 24 (3 W x 8 k-chunks).
// (harness-verified in R7)
__global__ __launch_bounds__(256) void wt_kernel(
    const float* __restrict__ Wq, const float* __restrict__ Wk,
    const float* __restrict__ Wv, _Float16* __restrict__ Wt) {
  __shared__ _Float16 t_lds[64][72];
  const int w = blockIdx.x >> 3, kb = blockIdx.x & 7;
  const float* W = (w == 0) ? Wq : (w == 1 ? Wk : Wv);
  const int tid = threadIdx.x;
  const int kk = tid >> 2;          // 0..63 k-row within chunk
  const int n0 = (tid & 3) * 16;    // 0,16,32,48
  const float4* src = (const float4*)(W + (size_t)(kb * 64 + kk) * 64 + n0);
  float4 f0 = src[0], f1 = src[1], f2 = src[2], f3 = src[3];
  t_lds[n0 +  0][kk] = (_Float16)f0.x; t_lds[n0 +  1][kk] = (_Float16)f0.y;
  t_lds[n0 +  2][kk] = (_Float16)f0.z; t_lds[n0 +  3][kk] = (_Float16)f0.w;
  t_lds[n0 +  4][kk] = (_Float16)f1.x; t_lds[n0 +  5][kk] = (_Float16)f1.y;
  t_lds[n0 +  6][kk] = (_Float16)f1.z; t_lds[n0 +  7][kk] = (_Float16)f1.w;
  t_lds[n0 +  8][kk] = (_Float16)f2.x; t_lds[n0 +  9][kk] = (_Float16)f2.y;
  t_lds[n0 + 10][kk] = (_Float16)f2.z; t_lds[n0 + 11][kk] = (_Float16)f2.w;
  t_lds[n0 + 12][kk] = (_Float16)f3.x; t_lds[n0 + 13][kk] = (_Float16)f3.y;
  t_lds[n0 + 14][kk] = (_Float16)f3.z; t_lds[n0 + 15][kk] = (_Float16)f3.w;
  __syncthreads();
  const int n = tid >> 2;
  const int koff = (tid & 3) * 16;
  half8 h0 = *(const half8*)&t_lds[n][koff];
  half8 h1 = *(const half8*)&t_lds[n][koff + 8];
  _Float16* dst = Wt + (size_t)(w * 64 + n) * 512 + kb * 64 + koff;
  *(half8*)dst = h0;
  *(half8*)(dst + 8) = h1;
}

// GEMM: out[m][n] = sum_k X[m][k] * W[k][n], M=65536 (128/block), K=512, N=64.
// NOUT=1: q = x*Wq (normal). NOUT=2: k = y*Wk (normal) + v = y*Wv (TRANSPOSED [b][h][t]).
// W staged from global Wt (f16 [n][k]) with vectorized half8 load + b128 LDS write.
template <int NOUT>
__global__ __launch_bounds__(256) void proj_kernel(
    const float* __restrict__ X, const _Float16* __restrict__ Wt0,
    const _Float16* __restrict__ Wt1, _Float16* __restrict__ O0,
    _Float16* __restrict__ O1t) {
  __shared__ _Float16 a_lds[128][40];        // 128 rows x 32 k, pad->40
  __shared__ _Float16 w_lds[NOUT][64][40];   // W^T: [n][k], pad->40
  __shared__ _Float16 vt_tile[NOUT == 2 ? 64 : 1][NOUT == 2 ? 136 : 1];  // [h][t]

  const int tid = threadIdx.x;
  const int row0 = blockIdx.x * 128;
  const int wv = tid >> 6;
  const int lane = tid & 63;
  const int l15 = lane & 15, quad = lane >> 4;

  floatx4 acc[2][4 * NOUT];
#pragma unroll
  for (int i = 0; i < 2; i++)
#pragma unroll
    for (int j = 0; j < 4 * NOUT; j++) acc[i][j] = (floatx4)0.f;

  const int arow = tid >> 1;            // 0..127
  const int ahalf = (tid & 1) * 16;     // 0 or 16 (k-cols)
  const int wn = tid >> 2;              // 0..63 (n row of Wt)
  const int wkoff = (tid & 3) * 8;      // 0,8,16,24 (k col within tile)

  for (int k0 = 0; k0 < 512; k0 += 32) {
    // ---- stage A tile (128 x 32), fp32 -> f16 ----
    {
      const float4* s4 = (const float4*)(X + (size_t)(row0 + arow) * 512 + k0 + ahalf);
      float4 f0 = s4[0], f1 = s4[1], f2 = s4[2], f3 = s4[3];
      *(half8*)&a_lds[arow][ahalf]     = cvt8(f0, f1);
      *(half8*)&a_lds[arow][ahalf + 8] = cvt8(f2, f3);
    }
    // ---- stage W^T tile(s): vectorized from global Wt (f16 [n][k]) ----
#pragma unroll
    for (int wi = 0; wi < NOUT; wi++) {
      const _Float16* wsrc = (wi ? Wt1 : Wt0) + (size_t)wn * 512 + k0 + wkoff;
      *(half8*)&w_lds[wi][wn][wkoff] = *(const half8*)wsrc;
    }
    __syncthreads();
    // ---- MFMA: each wave does 32 rows x (64*NOUT) cols ----
    half8 af0 = *(const half8*)&a_lds[wv * 32 + l15][quad * 8];
    half8 af1 = *(const half8*)&a_lds[wv * 32 + 16 + l15][quad * 8];
#pragma unroll
    for (int wi = 0; wi < NOUT; wi++)
#pragma unroll
      for (int j = 0; j < 4; j++) {
        half8 bf = *(const half8*)&w_lds[wi][j * 16 + l15][quad * 8];
        acc[0][wi * 4 + j] = MFMA16(af0, bf, acc[0][wi * 4 + j]);
        acc[1][wi * 4 + j] = MFMA16(af1, bf, acc[1][wi * 4 + j]);
      }
    __syncthreads();
  }
  // ---- epilogue: C/D layout col=l15, row=quad*4+r ----
#pragma unroll
  for (int i = 0; i < 2; i++)
#pragma unroll
    for (int j = 0; j < 4; j++)
#pragma unroll
      for (int r = 0; r < 4; r++) {
        int grow = row0 + wv * 32 + i * 16 + quad * 4 + r;
        O0[(size_t)grow * 64 + j * 16 + l15] = (_Float16)acc[i][j][r];
      }
  if constexpr (NOUT == 2) {
    // v (wi=1): transpose in LDS, store coalesced to Vt[b][h][t]
#pragma unroll
    for (int i = 0; i < 2; i++)
#pragma unroll
      for (int j = 0; j < 4; j++)
#pragma unroll
        for (int r = 0; r < 4; r++) {
          int tl = wv * 32 + i * 16 + quad * 4 + r;
          vt_tile[j * 16 + l15][tl] = (_Float16)acc[i][4 + j][r];
        }
    __syncthreads();
    const int b = row0 >> 8, t0 = row0 & 255;
    const int h = tid >> 2;
    const int seg = (tid & 3) * 32;
    _Float16* dst = O1t + ((size_t)b * 64 + h) * 256 + t0 + seg;
#pragma unroll
    for (int e = 0; e < 4; e++)
      *(half8*)(dst + e * 8) = *(const half8*)&vt_tile[h][seg + e * 8];
  }
}

// ---- Flash attention, causal (R15 best-known: LDS-staged K/Vt, 2 barriers/iter,
// T14 prefetch). Grid (qt=4, b=256); block 256 = 4 waves x 16 q-rows.
__global__ __launch_bounds__(256) void attn_kernel(
    const _Float16* __restrict__ Qw, const _Float16* __restrict__ Kw,
    const _Float16* __restrict__ Vt, float* __restrict__ Out) {
  __shared__ _Float16 k_lds[64][72];       // [s][h]
  __shared__ _Float16 vt_lds[64][72];      // [h][s]
  __shared__ _Float16 p_lds[4][16][72];    // per-wave P round-trip (wave-private)

  const int qt = blockIdx.x, bb = blockIdx.y;
  const int tid = threadIdx.x;
  const int wv = tid >> 6;
  const int lane = tid & 63;
  const int l15 = lane & 15, quad = lane >> 4;
  const float SCALE = 0.125f * 1.4426950408889634f;  // (1/sqrt(64)) * log2(e)
  const float NEG = -3.0e38f;

  const size_t qoff = ((size_t)bb * 256 + qt * 64 + wv * 16 + l15) * 64 + quad * 8;
  half8 qf0 = *(const half8*)(Qw + qoff);
  half8 qf1 = *(const half8*)(Qw + qoff + 32);

  floatx4 o[4];
#pragma unroll
  for (int t = 0; t < 4; t++) o[t] = (floatx4)0.f;
  float mrow[4], lrow[4];
#pragma unroll
  for (int r = 0; r < 4; r++) { mrow[r] = NEG; lrow[r] = 0.f; }

  const _Float16* Kb = Kw + (size_t)bb * 256 * 64;   // [t][h]
  const _Float16* Vb = Vt + (size_t)bb * 64 * 256;   // [h][t]

  const int srow = tid >> 2;          // 0..63
  const int sc = (tid & 3) * 16;      // 0,16,32,48

  // T14 prologue: issue j=0 K/Vt loads
  half8 kr0, kr1, vr0, vr1;
  {
    const half8* kp = (const half8*)(Kb + (size_t)srow * 64 + sc);
    kr0 = kp[0]; kr1 = kp[1];
    const half8* vp = (const half8*)(Vb + (size_t)srow * 256 + sc);
    vr0 = vp[0]; vr1 = vp[1];
  }

  for (int j = 0; j <= qt; j++) {
    // write staged regs -> LDS (coalesced, no transpose)
    *(half8*)&k_lds[srow][sc]      = kr0;
    *(half8*)&k_lds[srow][sc + 8]  = kr1;
    *(half8*)&vt_lds[srow][sc]     = vr0;
    *(half8*)&vt_lds[srow][sc + 8] = vr1;
    __syncthreads();

    // T14: issue j+1 loads now; latency hides under QK^T/softmax/PV
    if (j < qt) {
      const half8* kp = (const half8*)(Kb + (size_t)((j + 1) * 64 + srow) * 64 + sc);
      kr0 = kp[0]; kr1 = kp[1];
      const half8* vp = (const half8*)(Vb + (size_t)srow * 256 + (j + 1) * 64 + sc);
      vr0 = vp[0]; vr1 = vp[1];
    }

    // S = Q K^T : 16 q-rows x 64 s-cols per wave
    floatx4 sacc[4];
#pragma unroll
    for (int t = 0; t < 4; t++) sacc[t] = (floatx4)0.f;
#pragma unroll
    for (int t = 0; t < 4; t++) {
      half8 b0 = *(const half8*)&k_lds[t * 16 + l15][quad * 8];
      sacc[t] = MFMA16(qf0, b0, sacc[t]);
      half8 b1 = *(const half8*)&k_lds[t * 16 + l15][32 + quad * 8];
      sacc[t] = MFMA16(qf1, b1, sacc[t]);
    }

    // scale + causal mask (C/D layout: col = t*16+l15, row = quad*4+r)
    float y[4][4];
#pragma unroll
    for (int t = 0; t < 4; t++)
#pragma unroll
      for (int r = 0; r < 4; r++) y[t][r] = sacc[t][r] * SCALE;
    if (j == qt) {
#pragma unroll
      for (int t = 0; t < 4; t++)
#pragma unroll
        for (int r = 0; r < 4; r++)
          if (t * 16 + l15 > wv * 16 + quad * 4 + r) y[t][r] = NEG;
    }

    // online softmax per q-row (reduce across the quad's 16 lanes)
#pragma unroll
    for (int r = 0; r < 4; r++) {
      float mx = fmaxf(fmaxf(y[0][r], y[1][r]), fmaxf(y[2][r], y[3][r]));
#pragma unroll
      for (int off = 1; off < 16; off <<= 1) mx = fmaxf(mx, __shfl_xor(mx, off, 64));
      float mnew = fmaxf(mrow[r], mx);
      float al = exp2f(mrow[r] - mnew);
      mrow[r] = mnew;
      float rs = 0.f;
#pragma unroll
      for (int t = 0; t < 4; t++) {
        float p = exp2f(y[t][r] - mnew);
        y[t][r] = p;
        rs += p;
      }
#pragma unroll
      for (int off = 1; off < 16; off <<= 1) rs += __shfl_xor(rs, off, 64);
      lrow[r] = lrow[r] * al + rs;
      o[0][r] *= al; o[1][r] *= al; o[2][r] *= al; o[3][r] *= al;
    }

    // P: C/D layout -> wave-private LDS -> A layout (no barrier needed)
#pragma unroll
    for (int t = 0; t < 4; t++)
#pragma unroll
      for (int r = 0; r < 4; r++)
        p_lds[wv][quad * 4 + r][t * 16 + l15] = (_Float16)y[t][r];

    // O += P V
#pragma unroll
    for (int ss = 0; ss < 2; ss++) {
      half8 pa = *(const half8*)&p_lds[wv][l15][ss * 32 + quad * 8];
#pragma unroll
      for (int th = 0; th < 4; th++) {
        half8 vbf = *(const half8*)&vt_lds[th * 16 + l15][ss * 32 + quad * 8];
        o[th] = MFMA16(pa, vbf, o[th]);
      }
    }
    __syncthreads();  // all waves done reading k_lds/vt_lds before next overwrite
  }

  // normalize + store fp32
#pragma unroll
  for (int th = 0; th < 4; th++)
#pragma unroll
    for (int r = 0; r < 4; r++) {
      int grow = qt * 64 + wv * 16 + quad * 4 + r;
      Out[((size_t)bb * 256 + grow) * 64 + th * 16 + l15] = o[th][r] / lrow[r];
    }
}

extern "C" void kernel_launch(void* const* d_in, const int* in_sizes, int n_in,
                              void* d_out, int out_size, void* d_ws, size_t ws_size,
                              hipStream_t stream) {
  const float* x  = (const float*)d_in[0];
  const float* y  = (const float*)d_in[1];
  const float* Wq = (const float*)d_in[2];
  const float* Wk = (const float*)d_in[3];
  const float* Wv = (const float*)d_in[4];
  float* out = (float*)d_out;

  _Float16* qw = (_Float16*)d_ws;
  _Float16* kw = qw + (size_t)65536 * 64;
  _Float16* vt = kw + (size_t)65536 * 64;  // [256][64][256]
  _Float16* wt = vt + (size_t)65536 * 64;  // [3][64][512]

  wt_kernel<<<24, 256, 0, stream>>>(Wq, Wk, Wv, wt);
  proj_kernel<1><<<512, 256, 0, stream>>>(x, wt, nullptr, qw, nullptr);
  proj_kernel<2><<<512, 256, 0, stream>>>(y, wt + (size_t)64 * 512,
                                          wt + (size_t)2 * 64 * 512, kw, vt);
  attn_kernel<<<dim3(4, 256), 256, 0, stream>>>(qw, kw, vt, out);
}